// Round 3
// baseline (1206.807 us; speedup 1.0000x reference)
//
#include <hip/hip_runtime.h>

// SuperpixelPooling: per-(batch, superpixel) mean of 64-dim feature vectors.
// feat[8,512,512,64] f32, labels[8,512,512] i32 in [0,256) -> out[8,256,64] f32.
//
// Round-5 design: ALGORITHM INVERSION. r3/r4 post-mortem: the segment-owning
// scan (each block re-reads the whole batch label map hunting for its 2
// segments) is the bottleneck -- 268M pixel-visits of ballot+scalar-mask+
// branch work (~550-650 us); the gather was never dominant (r4's 16x MLP
// batching moved 750 -> 707 us only).
//
// New structure (one pass, pixel-parallel):
//   - 512 blocks x 512 thr; each block owns a contiguous 4096-pixel slab of
//     one batch. Features are read ONCE as a perfectly sequential coalesced
//     stream (each wave: contiguous 128 KB). Labels read once (8 MB total).
//   - Block-local histogram hist[256 segs][64 ch] f32 in LDS, accumulated
//     with native no-return ds_add_f32 (unsafeAtomicAdd). Row stride 65
//     dwords rotates the bank mapping per label -> expected ~2-way bank
//     aliasing (free per m136). 4 pixels/wave-step: lane=(slot 0..3, chg
//     0..15), float4/lane = 1 KB coalesced load per step.
//   - Counts via LDS u32 atomics (4 lanes/step).
//   - Flush: global f32 atomics straight into `out` (memset to 0 first;
//     34 MB atomic traffic, L2-resident). cnts in d_ws (8 KB).
//   - finalize kernel: out /= max(cnt,1) in place.
//
// Roofline: 512 MB feat + 8 MB labels + ~34 MB flush @ ~6 TB/s ~= 92 us.

#define NBATCH 8
#define NSEG 256
#define NCH 64
#define PPB (512 * 512)                       // 262144 pixels per batch
#define BLOCKS_PER_BATCH 64
#define PIX_PER_BLOCK (PPB / BLOCKS_PER_BATCH) // 4096
#define NWAVE 8                                // 512 threads
#define PIX_PER_WAVE (PIX_PER_BLOCK / NWAVE)   // 512
#define STAGE_PIX 256                          // labels staged per wave per stage
#define NSTAGE (PIX_PER_WAVE / STAGE_PIX)      // 2
#define STEPS (STAGE_PIX / 4)                  // 64 4-pixel steps per stage
#define HPAD 65                                // hist row stride in dwords (bank rotate)

__global__ __launch_bounds__(512, 4) void pool_kernel(const float* __restrict__ feat,
                                                      const int* __restrict__ sp,
                                                      float* __restrict__ outsum,
                                                      unsigned* __restrict__ cnts) {
    __shared__ float hist[NSEG][HPAD];        // 66560 B
    __shared__ unsigned cnt[NSEG];            // 1 KB
    __shared__ int lbl[NWAVE][STAGE_PIX];     // 8 KB   -> total 75.8 KB, 2 blocks/CU

    const int b = blockIdx.x >> 6;            // blockIdx / 64
    const int slab = blockIdx.x & 63;
    const int tid = threadIdx.x;
    const int lane = tid & 63;
    const int wave = tid >> 6;
    const int slot = lane >> 4;               // pixel slot 0..3
    const int chg = lane & 15;                // float4 channel group

    // zero histogram + counts
    for (int i = tid; i < NSEG * HPAD; i += 512) ((float*)hist)[i] = 0.0f;
    if (tid < NSEG) cnt[tid] = 0u;
    __syncthreads();

    const int pix0 = slab * PIX_PER_BLOCK + wave * PIX_PER_WAVE;  // batch-local
    const int* lp = sp + (size_t)b * PPB + pix0;
    const float4* fp = (const float4*)(feat + (size_t)b * PPB * NCH) + (size_t)pix0 * 16;

    for (int s = 0; s < NSTAGE; ++s) {
        // stage 256 labels for this wave (wave-synchronous, no barrier needed)
        int4 lv = ((const int4*)(lp + s * STAGE_PIX))[lane];
        ((int4*)lbl[wave])[lane] = lv;

        const float4* fs = fp + (size_t)s * STAGE_PIX * 16;

        // prefetch step 0
        int l_cur = lbl[wave][slot];
        float4 v_cur = fs[(size_t)slot * 16 + chg];

        for (int t = 0; t < STEPS; ++t) {
            const int tn = (t + 1 < STEPS) ? (t + 1) : t;   // clamped prefetch
            int l_nxt = lbl[wave][4 * tn + slot];
            float4 v_nxt = fs[(size_t)(4 * tn + slot) * 16 + chg];

            // accumulate pixel (slot) channels [4*chg, 4*chg+4) into hist row
            float* hrow = &hist[l_cur][chg * 4];
            unsafeAtomicAdd(&hrow[0], v_cur.x);
            unsafeAtomicAdd(&hrow[1], v_cur.y);
            unsafeAtomicAdd(&hrow[2], v_cur.z);
            unsafeAtomicAdd(&hrow[3], v_cur.w);
            if (chg == 0) atomicAdd(&cnt[l_cur], 1u);

            l_cur = l_nxt;
            v_cur = v_nxt;
        }
    }
    __syncthreads();

    // flush block-local histogram into global accumulators (device-scope f32
    // atomics, coalesced 64-dword bursts per wave)
    const size_t obase = (size_t)b * NSEG * NCH;
    for (int i = tid; i < NSEG * NCH; i += 512) {
        const int seg = i >> 6;
        const int ch = i & 63;
        unsafeAtomicAdd(&outsum[obase + i], hist[seg][ch]);
    }
    if (tid < NSEG) atomicAdd(&cnts[(size_t)b * NSEG + tid], cnt[tid]);
}

// out[idx] = sum[idx] / max(cnt,1), in place, float4-vectorized.
__global__ void finalize_kernel(float* __restrict__ outsum,
                                const unsigned* __restrict__ cnts) {
    const int idx4 = blockIdx.x * blockDim.x + threadIdx.x;  // over 32768 float4s
    const unsigned c = cnts[idx4 >> 4];                      // 16 float4 per segment
    const float inv = 1.0f / (float)(c > 0u ? c : 1u);
    float4 v = ((float4*)outsum)[idx4];
    v.x *= inv; v.y *= inv; v.z *= inv; v.w *= inv;
    ((float4*)outsum)[idx4] = v;
}

extern "C" void kernel_launch(void* const* d_in, const int* in_sizes, int n_in,
                              void* d_out, int out_size, void* d_ws, size_t ws_size,
                              hipStream_t stream) {
    const float* feat = (const float*)d_in[0];
    const int* sp = (const int*)d_in[1];
    float* out = (float*)d_out;
    unsigned* cnts = (unsigned*)d_ws;                 // 8 KB of workspace
    (void)in_sizes; (void)n_in; (void)out_size; (void)ws_size;

    hipMemsetAsync(d_out, 0, (size_t)NBATCH * NSEG * NCH * sizeof(float), stream);
    hipMemsetAsync(d_ws, 0, (size_t)NBATCH * NSEG * sizeof(unsigned), stream);
    pool_kernel<<<NBATCH * BLOCKS_PER_BATCH, 512, 0, stream>>>(feat, sp, out, cnts);
    finalize_kernel<<<(NBATCH * NSEG * NCH / 4) / 256, 256, 0, stream>>>(out, cnts);
}

// Round 6
// 706.163 us; speedup vs baseline: 1.7090x; 1.7090x over previous
//
#include <hip/hip_runtime.h>

// SuperpixelPooling: per-(batch, superpixel) mean of 64-dim feature vectors.
// feat[8,512,512,64] f32, labels[8,512,512] i32 in [0,256) -> out[8,256,64] f32.
//
// Round-6: keep r5's pixel-parallel inversion, ELIMINATE ALL LDS ATOMICS.
// r5 post-mortem: pool=684us with VALUBusy 0.73%, HBM 5.6% -> nothing busy;
// 1.64M cyc/CU / 8192 ds_add_f32 wave-ops = ~200 cyc per wave-wide LDS atomic
// (= r1's number). LDS atomics serialize per-lane in HW; bank tricks can't fix.
// Also: 1207us total vs 684 pool -> ~520us gap, suspected hipMemsetAsync
// breaking graph capture -> replaced by an init kernel (3 pure launches).
//
// Structure:
//   - 512 blocks x 512 thr; block owns a contiguous 4096-pixel slab.
//   - Wave w exclusively owns segments [32w, 32w+32) (owner = label>>5).
//     All 8 waves scan all 16 label chunks (int4 loads, L1-broadcast).
//   - Vectorized claim: ballot(owner==wave) + mbcnt rank -> owned lanes write
//     packed (label<<12 | pix) to a per-wave LDS queue. No serial mask walk.
//   - Drain in groups of 4 with issue-ahead-one-group: 4 x 256B coalesced row
//     loads in flight per wave (4096 waves x ~1KB ~= 4MB in flight > 2.4MB
//     Little's-law knee). hist[s][lane] += f is PLAIN ds_read/v_add/ds_write:
//     rows are wave-exclusive (no cross-wave race), same-wave LDS ordering
//     makes back-to-back rmw of equal labels correct. Queue padded to x4 with
//     per-wave dummy rows (256+w) so the drain is branch-free.
//   - No barriers in the main loop (waves fully independent until flush).
//   - Flush: global no-return f32 atomics into out (L2-resident), cnt -> ws.
//   - init kernel zeroes out+cnts; finalize divides by counts.
//
// Roofline: 512 MB feat + 8 MB labels + ~34 MB flush @ ~6 TB/s ~= 92 us.

#define NBATCH 8
#define NSEG 256
#define NCH 64
#define PPB (512 * 512)                        // 262144 pixels per batch
#define BLOCKS_PER_BATCH 64
#define PIX_PER_BLOCK 4096
#define NWAVE 8
#define NCHUNK 16                              // 4096 / 256
#define CHUNK_PIX 256
#define QMAX 256                               // worst case: whole chunk owned
#define NROWS (NSEG + NWAVE)                   // 256 real + 8 dummy rows

__global__ __launch_bounds__(512, 4) void pool_kernel(const float* __restrict__ feat,
                                                      const int* __restrict__ sp,
                                                      float* __restrict__ outsum,
                                                      unsigned* __restrict__ cnts) {
    __shared__ float hist[NROWS * NCH];        // 67.6 KB, rows wave-exclusive
    __shared__ unsigned cnt[NROWS];            // 1 KB
    __shared__ int qd[NWAVE][QMAX];            // 8 KB  -> total ~76.8 KB, 2 blk/CU

    const int b = blockIdx.x >> 6;
    const int slab = blockIdx.x & 63;
    const int tid = threadIdx.x;
    const int lane = tid & 63;
    const int wave = tid >> 6;

    for (int i = tid; i < NROWS * NCH; i += 512) hist[i] = 0.0f;
    if (tid < NROWS) cnt[tid] = 0u;
    __syncthreads();

    const int pixbase = slab * PIX_PER_BLOCK;  // batch-local pixel offset
    const int4* lp4 = (const int4*)(sp + (size_t)b * PPB + pixbase);
    const float* fb = feat + ((size_t)b * PPB + pixbase) * NCH + lane;

    const int dummy_e = (NSEG + wave) << 12;   // pad entry: dummy row, pixel 0
    int* q = qd[wave];

    int4 lab = lp4[lane];                      // chunk 0 labels (256 per wave)
    for (int c = 0; c < NCHUNK; ++c) {
        const int cn = (c + 1 < NCHUNK) ? (c + 1) : c;
        int4 nlab = lp4[cn * 64 + lane];       // prefetch next chunk's labels
        int qn = 0;
        const int pbase = c * CHUNK_PIX + 4 * lane;  // lane's first pixel (local)

        // ---- vectorized claim: ballot + mbcnt rank-compaction ----
#define PUSH(SV, CC)                                                          \
        {                                                                     \
            const int s_ = (SV);                                              \
            const bool own_ = ((s_ >> 5) == wave);                            \
            const unsigned long long m_ = __ballot(own_);                     \
            if (own_) {                                                       \
                const int r_ = __builtin_amdgcn_mbcnt_hi(                     \
                    (unsigned)(m_ >> 32),                                     \
                    __builtin_amdgcn_mbcnt_lo((unsigned)m_, 0));              \
                q[qn + r_] = (s_ << 12) | (pbase + (CC));                     \
            }                                                                 \
            qn += __builtin_popcountll(m_);                                   \
        }
        PUSH(lab.x, 0) PUSH(lab.y, 1) PUSH(lab.z, 2) PUSH(lab.w, 3)
#undef PUSH

        // pad to a multiple of 4 with dummy entries (branch-free drain)
        const int npad = (4 - (qn & 3)) & 3;
        if (lane < npad) q[qn + lane] = dummy_e;
        qn += npad;

        // ---- drain: groups of 4, issue group g+1 before consuming group g ----
        const int ng = qn >> 2;
        if (ng) {
            int4 eA = *(const int4*)&q[0];                 // uniform b128 broadcast
            float fA0 = fb[(size_t)(eA.x & 4095) * NCH];
            float fA1 = fb[(size_t)(eA.y & 4095) * NCH];
            float fA2 = fb[(size_t)(eA.z & 4095) * NCH];
            float fA3 = fb[(size_t)(eA.w & 4095) * NCH];
            for (int g = 1; g < ng; ++g) {
                int4 eB = *(const int4*)&q[g * 4];
                float fB0 = fb[(size_t)(eB.x & 4095) * NCH];
                float fB1 = fb[(size_t)(eB.y & 4095) * NCH];
                float fB2 = fb[(size_t)(eB.z & 4095) * NCH];
                float fB3 = fb[(size_t)(eB.w & 4095) * NCH];

                hist[(eA.x >> 12) * NCH + lane] += fA0;
                if (lane == 0) cnt[eA.x >> 12]++;
                hist[(eA.y >> 12) * NCH + lane] += fA1;
                if (lane == 0) cnt[eA.y >> 12]++;
                hist[(eA.z >> 12) * NCH + lane] += fA2;
                if (lane == 0) cnt[eA.z >> 12]++;
                hist[(eA.w >> 12) * NCH + lane] += fA3;
                if (lane == 0) cnt[eA.w >> 12]++;

                eA = eB; fA0 = fB0; fA1 = fB1; fA2 = fB2; fA3 = fB3;
            }
            hist[(eA.x >> 12) * NCH + lane] += fA0;
            if (lane == 0) cnt[eA.x >> 12]++;
            hist[(eA.y >> 12) * NCH + lane] += fA1;
            if (lane == 0) cnt[eA.y >> 12]++;
            hist[(eA.z >> 12) * NCH + lane] += fA2;
            if (lane == 0) cnt[eA.z >> 12]++;
            hist[(eA.w >> 12) * NCH + lane] += fA3;
            if (lane == 0) cnt[eA.w >> 12]++;
        }
        lab = nlab;
    }
    __syncthreads();

    // flush real rows (0..255) with no-return device atomics; dummies dropped
    const size_t obase = (size_t)b * NSEG * NCH;
    for (int i = tid; i < NSEG * NCH; i += 512)
        unsafeAtomicAdd(&outsum[obase + i], hist[i]);
    if (tid < NSEG) atomicAdd(&cnts[(size_t)b * NSEG + tid], cnt[tid]);
}

// zero out (2 MB) + cnts (8 KB) -- replaces hipMemsetAsync (graph-capture safe)
__global__ void init_kernel(float* __restrict__ outsum, unsigned* __restrict__ cnts) {
    const int i = blockIdx.x * 256 + threadIdx.x;        // 131072 float4s
    ((float4*)outsum)[i] = make_float4(0.f, 0.f, 0.f, 0.f);
    if (i < (NBATCH * NSEG) / 4) ((uint4*)cnts)[i] = make_uint4(0u, 0u, 0u, 0u);
}

// out[idx] = sum[idx] / max(cnt,1), in place, float4-vectorized.
__global__ void finalize_kernel(float* __restrict__ outsum,
                                const unsigned* __restrict__ cnts) {
    const int idx4 = blockIdx.x * blockDim.x + threadIdx.x;  // 32768 float4s
    const unsigned c = cnts[idx4 >> 4];                      // 16 float4 / segment
    const float inv = 1.0f / (float)(c > 0u ? c : 1u);
    float4 v = ((float4*)outsum)[idx4];
    v.x *= inv; v.y *= inv; v.z *= inv; v.w *= inv;
    ((float4*)outsum)[idx4] = v;
}

extern "C" void kernel_launch(void* const* d_in, const int* in_sizes, int n_in,
                              void* d_out, int out_size, void* d_ws, size_t ws_size,
                              hipStream_t stream) {
    const float* feat = (const float*)d_in[0];
    const int* sp = (const int*)d_in[1];
    float* out = (float*)d_out;
    unsigned* cnts = (unsigned*)d_ws;                 // 8 KB of workspace
    (void)in_sizes; (void)n_in; (void)out_size; (void)ws_size;

    init_kernel<<<512, 256, 0, stream>>>(out, cnts);
    pool_kernel<<<NBATCH * BLOCKS_PER_BATCH, 512, 0, stream>>>(feat, sp, out, cnts);
    finalize_kernel<<<(NBATCH * NSEG * NCH / 4) / 256, 256, 0, stream>>>(out, cnts);
}

// Round 7
// 694.235 us; speedup vs baseline: 1.7383x; 1.0172x over previous
//
#include <hip/hip_runtime.h>

// SuperpixelPooling: per-(batch, superpixel) mean of 64-dim feature vectors.
// feat[8,512,512,64] f32, labels[8,512,512] i32 in [0,256) -> out[8,256,64] f32.
//
// Round-7. r6 post-mortem: pool dropped below the top-5 cutoff (<330us) after
// removing LDS atomics, but total dur stayed ~706us. Cross-round arithmetic:
// the harness re-poisons the 2 GiB workspace every iteration (2.147GB
// fillBufferAligned @ ~332us) INSIDE the timed region -> ~335us fixed floor.
// Our controllable budget is ~350us vs a ~92us pool roofline.
//
// r7 changes:
//   1. Drain pipeline deepened: groups of 8 pixels, issue-ahead-one-group ->
//      8 independent 256B row loads in flight per wave (8MB chip-wide, well
//      past the ~2.4MB Little's-law knee). Per-pixel hist rmw stays strictly
//      sequential (same-wave LDS ordering; batching rmws would lose updates
//      on duplicate labels within a group).
//   2. Counts moved out of the drain: one divergent ds_add_u32 per PUSH at
//      claim time (~16 active lanes, mostly distinct addresses) replaces 512
//      per-pixel lane0 exec-mask toggles + scalar rmws.
//   3. Deterministic 2-launch pipeline: pool writes per-block partial
//      histograms (33.5MB) + counts to ws with plain coalesced float4 stores;
//      reduce_kernel (2048 blocks, one per (batch,segment)) sums 64 slab
//      partials, divides by total count, writes out. No global atomics, no
//      init kernel, nothing to zero.
//
// Structure (pool): 512 blocks x 512 thr; block owns a 4096-pixel slab; wave
// w owns segments [32w,32w+32). ballot+mbcnt rank-compaction pushes packed
// (label<<12|pix) entries to a per-wave LDS queue; queue padded to x8 with
// per-wave dummy rows (256+w) so the drain is branch-free.

#define NBATCH 8
#define NSEG 256
#define NCH 64
#define PPB (512 * 512)                        // 262144 pixels per batch
#define BPB 64                                 // blocks per batch
#define PIX_PER_BLOCK 4096
#define NWAVE 8
#define NCHUNK 16                              // 4096 / 256
#define CHUNK_PIX 256
#define QMAX 264                               // 256 worst case + 7 pad, 16B-mult
#define NROWS (NSEG + NWAVE)                   // 256 real + 8 dummy rows

__global__ __launch_bounds__(512, 2) void pool_kernel(const float* __restrict__ feat,
                                                      const int* __restrict__ sp,
                                                      float* __restrict__ pspart,
                                                      unsigned* __restrict__ pscnt) {
    __shared__ float hist[NROWS * NCH];        // 67.6 KB, rows wave-exclusive
    __shared__ unsigned cnt[NROWS];            // 1 KB
    __shared__ int qd[NWAVE][QMAX];            // 8.4 KB -> ~77 KB, 2 blk/CU

    const int b = blockIdx.x >> 6;
    const int slab = blockIdx.x & 63;
    const int tid = threadIdx.x;
    const int lane = tid & 63;
    const int wave = tid >> 6;

    for (int i = tid; i < (NROWS * NCH) / 4; i += 512)
        ((float4*)hist)[i] = make_float4(0.f, 0.f, 0.f, 0.f);
    if (tid < NROWS) cnt[tid] = 0u;
    __syncthreads();

    const int pixbase = slab * PIX_PER_BLOCK;  // batch-local pixel offset
    const int4* lp4 = (const int4*)(sp + (size_t)b * PPB + pixbase);
    const float* fb = feat + ((size_t)b * PPB + pixbase) * NCH + lane;

    const int dummy_e = (NSEG + wave) << 12;   // pad entry: dummy row, pixel 0
    int* q = qd[wave];

    int4 lab = lp4[lane];                      // chunk 0 labels
    for (int c = 0; c < NCHUNK; ++c) {
        const int cn = (c + 1 < NCHUNK) ? (c + 1) : c;
        int4 nlab = lp4[cn * 64 + lane];       // prefetch next chunk's labels
        int qn = 0;
        const int pbase = c * CHUNK_PIX + 4 * lane;

        // ---- claim: ballot + mbcnt rank-compaction; counts via ds_add ----
#define PUSH(SV, CC)                                                          \
        {                                                                     \
            const int s_ = (SV);                                              \
            const bool own_ = ((s_ >> 5) == wave);                            \
            const unsigned long long m_ = __ballot(own_);                     \
            if (own_) {                                                       \
                const int r_ = __builtin_amdgcn_mbcnt_hi(                     \
                    (unsigned)(m_ >> 32),                                     \
                    __builtin_amdgcn_mbcnt_lo((unsigned)m_, 0));              \
                q[qn + r_] = (s_ << 12) | (pbase + (CC));                     \
                atomicAdd(&cnt[s_], 1u);                                      \
            }                                                                 \
            qn += __builtin_popcountll(m_);                                   \
        }
        PUSH(lab.x, 0) PUSH(lab.y, 1) PUSH(lab.z, 2) PUSH(lab.w, 3)
#undef PUSH

        // pad to a multiple of 8 with dummy entries (branch-free drain)
        const int npad = (8 - (qn & 7)) & 7;
        if (lane < npad) q[qn + lane] = dummy_e;
        qn += npad;

        // ---- drain: groups of 8, issue group g+1 before consuming group g ----
        const int ng = qn >> 3;
        if (ng) {
            int4 a0 = *(const int4*)&q[0];     // uniform b128 broadcasts
            int4 a1 = *(const int4*)&q[4];
            float f0 = fb[(size_t)(a0.x & 4095) * NCH];
            float f1 = fb[(size_t)(a0.y & 4095) * NCH];
            float f2 = fb[(size_t)(a0.z & 4095) * NCH];
            float f3 = fb[(size_t)(a0.w & 4095) * NCH];
            float f4 = fb[(size_t)(a1.x & 4095) * NCH];
            float f5 = fb[(size_t)(a1.y & 4095) * NCH];
            float f6 = fb[(size_t)(a1.z & 4095) * NCH];
            float f7 = fb[(size_t)(a1.w & 4095) * NCH];
            for (int g = 1; g < ng; ++g) {
                int4 b0 = *(const int4*)&q[g * 8];
                int4 b1 = *(const int4*)&q[g * 8 + 4];
                float h0 = fb[(size_t)(b0.x & 4095) * NCH];
                float h1 = fb[(size_t)(b0.y & 4095) * NCH];
                float h2 = fb[(size_t)(b0.z & 4095) * NCH];
                float h3 = fb[(size_t)(b0.w & 4095) * NCH];
                float h4 = fb[(size_t)(b1.x & 4095) * NCH];
                float h5 = fb[(size_t)(b1.y & 4095) * NCH];
                float h6 = fb[(size_t)(b1.z & 4095) * NCH];
                float h7 = fb[(size_t)(b1.w & 4095) * NCH];

                hist[(a0.x >> 12) * NCH + lane] += f0;   // sequential rmw:
                hist[(a0.y >> 12) * NCH + lane] += f1;   // ordered within wave,
                hist[(a0.z >> 12) * NCH + lane] += f2;   // dup-label safe
                hist[(a0.w >> 12) * NCH + lane] += f3;
                hist[(a1.x >> 12) * NCH + lane] += f4;
                hist[(a1.y >> 12) * NCH + lane] += f5;
                hist[(a1.z >> 12) * NCH + lane] += f6;
                hist[(a1.w >> 12) * NCH + lane] += f7;

                a0 = b0; a1 = b1;
                f0 = h0; f1 = h1; f2 = h2; f3 = h3;
                f4 = h4; f5 = h5; f6 = h6; f7 = h7;
            }
            hist[(a0.x >> 12) * NCH + lane] += f0;
            hist[(a0.y >> 12) * NCH + lane] += f1;
            hist[(a0.z >> 12) * NCH + lane] += f2;
            hist[(a0.w >> 12) * NCH + lane] += f3;
            hist[(a1.x >> 12) * NCH + lane] += f4;
            hist[(a1.y >> 12) * NCH + lane] += f5;
            hist[(a1.z >> 12) * NCH + lane] += f6;
            hist[(a1.w >> 12) * NCH + lane] += f7;
        }
        lab = nlab;
    }
    __syncthreads();

    // flush per-block partials: plain coalesced float4 stores (no atomics)
    float4* wp = (float4*)(pspart + (size_t)blockIdx.x * (NSEG * NCH));
    const float4* hs = (const float4*)hist;    // first 256 rows are contiguous
    for (int i = tid; i < (NSEG * NCH) / 4; i += 512) wp[i] = hs[i];
    if (tid < NSEG) pscnt[(size_t)blockIdx.x * NSEG + tid] = cnt[tid];
}

// One block (1 wave) per (batch, segment): sum 64 slab partials, divide.
__global__ __launch_bounds__(64) void reduce_kernel(const float* __restrict__ pspart,
                                                    const unsigned* __restrict__ pscnt,
                                                    float* __restrict__ out) {
    const int bs = blockIdx.x;                 // b * NSEG + seg
    const int bnum = bs >> 8;
    const int seg = bs & 255;
    const int lane = threadIdx.x;              // 64 = channel

    const float* base = pspart + ((size_t)bnum * BPB * NSEG + seg) * NCH + lane;
    float acc = 0.f;
#pragma unroll
    for (int s = 0; s < BPB; ++s)              // 64 independent 256B row reads
        acc += base[(size_t)s * NSEG * NCH];

    unsigned c = pscnt[((size_t)bnum * BPB + lane) * NSEG + seg];  // lane = slab
    for (int o = 32; o; o >>= 1) c += __shfl_xor(c, o);            // total in all lanes

    out[(size_t)bs * NCH + lane] = acc / (float)(c > 0u ? c : 1u);
}

extern "C" void kernel_launch(void* const* d_in, const int* in_sizes, int n_in,
                              void* d_out, int out_size, void* d_ws, size_t ws_size,
                              hipStream_t stream) {
    const float* feat = (const float*)d_in[0];
    const int* sp = (const int*)d_in[1];
    float* out = (float*)d_out;
    float* pspart = (float*)d_ws;                               // 33.5 MB
    unsigned* pscnt = (unsigned*)((char*)d_ws + (size_t)NBATCH * BPB * NSEG * NCH * 4);
    (void)in_sizes; (void)n_in; (void)out_size; (void)ws_size;

    pool_kernel<<<NBATCH * BPB, 512, 0, stream>>>(feat, sp, pspart, pscnt);
    reduce_kernel<<<NBATCH * NSEG, 64, 0, stream>>>(pspart, pscnt, out);
}